// Round 3
// baseline (11595.293 us; speedup 1.0000x reference)
//
#include <hip/hip_runtime.h>
#include <math.h>

typedef __bf16 bf16_t;
typedef bf16_t bf16x8 __attribute__((ext_vector_type(8)));
typedef bf16_t bf16x4 __attribute__((ext_vector_type(4)));
typedef float  f32x4  __attribute__((ext_vector_type(4)));

#define NB 32
#define NN 512
#define NH 64
#define NF 384

static __device__ __forceinline__ f32x4 mfma16(bf16x8 a, bf16x8 b, f32x4 c){
  return __builtin_amdgcn_mfma_f32_16x16x32_bf16(a, b, c, 0, 0, 0);
}

// ---------------- setup kernels ----------------------------------------------------
__global__ __launch_bounds__(256) void k_convert_S(const float* __restrict__ S,
                                                   bf16_t* __restrict__ Sb){
  int i = blockIdx.x * 256 + threadIdx.x;
  f32x4 v = *(const f32x4*)&S[(size_t)i * 4];
  bf16x4 o;
  #pragma unroll
  for (int q = 0; q < 4; ++q) o[q] = (bf16_t)v[q];
  *(bf16x4*)&Sb[(size_t)i * 4] = o;
}

__global__ __launch_bounds__(256) void k_s2(const float* __restrict__ S,
                                            bf16_t* __restrict__ S2b){
  int idx = blockIdx.x * 256 + threadIdx.x;
  int n = idx >> 9, m = idx & 511;
  float acc = 0.f;
  for (int k = 0; k < 512; ++k) acc += S[n * 512 + k] * S[k * 512 + m];
  S2b[idx] = (bf16_t)acc;
}

__global__ __launch_bounds__(256) void k_transW(const float* __restrict__ W,
                                                bf16_t* __restrict__ Wt, int OD){
  int i = blockIdx.x * 256 + threadIdx.x;
  int total = 2 * NF * OD;
  if (i >= total) return;
  int l = i / (NF * OD), rem = i - l * (NF * OD);
  int o = rem / NF, f = rem - o * NF;
  Wt[i] = (bf16_t)W[(size_t)(l * NF + f) * OD + o];
}

// ---------------- group barrier (8 co-resident blocks) -----------------------------
__device__ __forceinline__ void gbarrier(unsigned* cnt, unsigned* gen){
  __syncthreads();
  if (threadIdx.x == 0){
    __threadfence();
    unsigned gc = __hip_atomic_load(gen, __ATOMIC_RELAXED, __HIP_MEMORY_SCOPE_AGENT);
    unsigned a  = __hip_atomic_fetch_add(cnt, 1u, __ATOMIC_ACQ_REL, __HIP_MEMORY_SCOPE_AGENT);
    if (a == 7u){
      __hip_atomic_store(cnt, 0u, __ATOMIC_RELAXED, __HIP_MEMORY_SCOPE_AGENT);
      __hip_atomic_fetch_add(gen, 1u, __ATOMIC_RELEASE, __HIP_MEMORY_SCOPE_AGENT);
    } else {
      int sp = 0;
      while (__hip_atomic_load(gen, __ATOMIC_ACQUIRE, __HIP_MEMORY_SCOPE_AGENT) == gc){
        __builtin_amdgcn_s_sleep(2);
        if (++sp > (1 << 24)) break;
      }
    }
    __threadfence();
  }
  __syncthreads();
}

// ---------------- the persistent kernel --------------------------------------------
// grid 256 x 512. block: batch b = bid&31 (group of 8 via bid>>5), rows n0=g*64.
// LDS: S rows (64KB, swz) + S2 rows (64KB, swz) + 32KB union (Bst dbuf / WT+feat / tile)
__global__ void __launch_bounds__(512, 2) k_main(
    const float* __restrict__ inputs, const float* __restrict__ h0,
    const bf16_t* __restrict__ Sb, const bf16_t* __restrict__ S2b,
    const bf16_t* __restrict__ WgTa, const bf16_t* __restrict__ WcTa,
    const float* __restrict__ bga, const float* __restrict__ bca,
    float* __restrict__ hTf, bf16_t* __restrict__ hNb,
    bf16_t* __restrict__ rhN, float* __restrict__ uT,
    unsigned* __restrict__ bar, float* __restrict__ outp)
{
  extern __shared__ char smem[];
  char* const SR  = smem;
  char* const S2R = smem + 65536;
  char* const UNI = smem + 131072;
  char* const BQ0 = UNI;
  char* const BQ1 = UNI + 16384;
  char* const WT  = UNI;
  char* const FT  = UNI + 16384;
  float* const TT = (float*)UNI;     // [64][68] f32 epilogue tile

  const int bid = blockIdx.x;
  const int b = bid & 31;
  const int g = bid >> 5;
  const int n0 = g * 64;
  const int tid = threadIdx.x;
  const int lane = tid & 63;
  const int w = tid >> 6;
  const int fr = lane & 15;
  const int klg = lane >> 4;
  const int ko = klg * 8;
  const int ro = klg * 4;
  unsigned* const bcnt = bar + b * 32;
  unsigned* const bgen = bcnt + 1;

  // ---- persistent S / S2 rows into LDS (XOR-swizzled) ----
  {
    const bf16_t* s1 = Sb  + (size_t)n0 * NN;
    const bf16_t* s2 = S2b + (size_t)n0 * NN;
    for (int i = tid; i < 4096; i += 512){
      int r = i >> 6, gr = i & 63;
      int off = (r * 1024 + gr * 16) ^ ((r & 7) << 4);
      *(bf16x8*)(SR  + off) = *(const bf16x8*)&s1[r * NN + gr * 8];
      *(bf16x8*)(S2R + off) = *(const bf16x8*)&s2[r * NN + gr * 8];
    }
  }
  __syncthreads();

  float* const cur = outp + (size_t)2 * NB * NN * NH;

  for (int l = 0; l < 2; ++l){
    const bf16_t* const Wg = WgTa + (size_t)l * 128 * NF;
    const bf16_t* const Wc = WcTa + (size_t)l * 64 * NF;
    const float* const bg = bga + l * 128;
    const float* const bc = bca + l * 64;

    // ---- h init: h0[l] rows -> hNb (rows) + hTf (transposed via TT) ----
    {
      const float* hsrc = h0 + (size_t)l * NB * NN * NH + ((size_t)b * NN + n0) * NH;
      int n = tid >> 3, oq = tid & 7;
      #pragma unroll
      for (int s = 0; s < 2; ++s){
        int o4 = (oq + s * 8) * 4;
        f32x4 v = *(const f32x4*)&hsrc[n * NH + o4];
        bf16x4 bv;
        #pragma unroll
        for (int q = 0; q < 4; ++q) bv[q] = (bf16_t)v[q];
        *(bf16x4*)&hNb[((size_t)b * NN + n0 + n) * NH + o4] = bv;
        #pragma unroll
        for (int q = 0; q < 4; ++q) TT[(o4 + q) * 68 + n] = v[q];
      }
      __syncthreads();
      int o = tid >> 3, cq = tid & 7;
      #pragma unroll
      for (int s = 0; s < 2; ++s){
        int nq = (cq + s * 8) * 4;
        f32x4 v = *(const f32x4*)&TT[o * 68 + nq];
        *(f32x4*)&hTf[((size_t)b * NH + o) * NN + n0 + nq] = v;
      }
    }
    gbarrier(bcnt, bgen);

    for (int t = 0; t < 48; ++t){
      const float* const xs = ((l == 0) ? inputs : cur)
                              + (size_t)t * NB * NN * NH + (size_t)b * NN * NH;

      // ================= GATE =================
      f32x4 ga[8];
      #pragma unroll
      for (int i = 0; i < 8; ++i) ga[i] = (f32x4){0.f, 0.f, 0.f, 0.f};
      {
        const char* const Sbase = (w >= 4) ? S2R : SR;
        const int arow = (w & 3) * 16 + fr;
        f32x4 px0[2], px1[2]; bf16x8 ph[2];
        auto gpref = [&](int ch, int p){
          int m = ch * 64 + lane;
          const float* xr = xs + (size_t)m * NH + w * 8;
          px0[p] = *(const f32x4*)xr;
          px1[p] = *(const f32x4*)(xr + 4);
          ph[p]  = *(const bf16x8*)&hNb[((size_t)b * NN + m) * NH + w * 8];
        };
        auto gwrite = [&](int p, char* buf){
          #pragma unroll
          for (int q = 0; q < 8; ++q){
            int c = w * 8 + q;
            float v = (q < 4) ? px0[p][q] : px1[p][q - 4];
            *(bf16_t*)(buf + ((c * 128 + lane * 2) ^ ((c & 7) << 4))) = (bf16_t)v;
            int c2 = 64 + c;
            *(bf16_t*)(buf + ((c2 * 128 + lane * 2) ^ ((c2 & 7) << 4))) = ph[p][q];
          }
        };
        auto gmm = [&](const char* buf, int ch){
          #pragma unroll
          for (int ktl = 0; ktl < 2; ++ktl){
            int kb = (ch * 64 + ktl * 32 + ko) * 2;
            bf16x8 af = *(const bf16x8*)(Sbase + ((arow * 1024 + kb) ^ ((arow & 7) << 4)));
            int kl = (ktl * 32 + ko) * 2;
            #pragma unroll
            for (int ct = 0; ct < 8; ++ct){
              int brow = ct * 16 + fr;
              bf16x8 bf_ = *(const bf16x8*)(buf + ((brow * 128 + kl) ^ ((brow & 7) << 4)));
              ga[ct] = mfma16(af, bf_, ga[ct]);
            }
          }
        };
        gpref(0, 0);
        __syncthreads();
        gwrite(0, BQ0);
        gpref(1, 1);
        __syncthreads();
        #pragma unroll
        for (int ch = 0; ch < 8; ++ch){
          gmm((ch & 1) ? BQ1 : BQ0, ch);
          if (ch < 7){
            __syncthreads();
            gwrite((ch + 1) & 1, (ch & 1) ? BQ0 : BQ1);
            if (ch < 6) gpref(ch + 2, ch & 1);
            __syncthreads();
          }
        }
      }
      // gate dense: 6 chunks of 64 f
      f32x4 gd[4];
      #pragma unroll
      for (int i = 0; i < 4; ++i) gd[i] = (f32x4){0.f, 0.f, 0.f, 0.f};
      #pragma unroll
      for (int j = 0; j < 6; ++j){
        __syncthreads();
        { // stage Wg chunk [128 o][64 f]
          int o = tid >> 2, g2 = tid & 3;
          #pragma unroll
          for (int s = 0; s < 2; ++s){
            int gr = g2 + s * 4;
            bf16x8 v = *(const bf16x8*)&Wg[(size_t)o * NF + j * 64 + gr * 8];
            *(bf16x8*)(WT + ((o * 128 + gr * 16) ^ ((o & 7) << 4))) = v;
          }
        }
        if (j == 0){
          int n = tid >> 3, f16 = tid & 7;
          const float* xr = xs + (size_t)(n0 + n) * NH + f16 * 8;
          f32x4 a = *(const f32x4*)xr, b2 = *(const f32x4*)(xr + 4);
          bf16x8 v;
          #pragma unroll
          for (int q = 0; q < 4; ++q){ v[q] = (bf16_t)a[q]; v[q + 4] = (bf16_t)b2[q]; }
          *(bf16x8*)(FT + ((n * 128 + f16 * 16) ^ ((n & 7) << 4))) = v;
        } else if (j == 1){
          int n = tid >> 3, f16 = tid & 7;
          bf16x8 v = *(const bf16x8*)&hNb[((size_t)b * NN + n0 + n) * NH + f16 * 8];
          *(bf16x8*)(FT + ((n * 128 + f16 * 16) ^ ((n & 7) << 4))) = v;
        } else if (j == 2 || j == 3){
          if (w < 4){
            #pragma unroll
            for (int ct = 0; ct < 4; ++ct){
              int c = ct * 16 + fr;
              #pragma unroll
              for (int r = 0; r < 4; ++r){
                int n = (w & 3) * 16 + ro + r;
                float v = (j == 2) ? ga[ct][r] : ga[ct + 4][r];
                *(bf16_t*)(FT + ((n * 128 + c * 2) ^ ((n & 7) << 4))) = (bf16_t)v;
              }
            }
          }
        } else {
          if (w >= 4){
            #pragma unroll
            for (int ct = 0; ct < 4; ++ct){
              int c = ct * 16 + fr;
              #pragma unroll
              for (int r = 0; r < 4; ++r){
                int n = (w & 3) * 16 + ro + r;
                float base = (j == 4) ? xs[(size_t)(n0 + n) * NH + c]
                                      : (float)hNb[((size_t)b * NN + n0 + n) * NH + c];
                float v = 2.f * ((j == 4) ? ga[ct][r] : ga[ct + 4][r]) - base;
                *(bf16_t*)(FT + ((n * 128 + c * 2) ^ ((n & 7) << 4))) = (bf16_t)v;
              }
            }
          }
        }
        __syncthreads();
        {
          int anr = (w & 3) * 16 + fr, oh = w >> 2;
          #pragma unroll
          for (int ktl = 0; ktl < 2; ++ktl){
            int kb = (ktl * 32 + ko) * 2;
            bf16x8 af = *(const bf16x8*)(FT + ((anr * 128 + kb) ^ ((anr & 7) << 4)));
            #pragma unroll
            for (int ot = 0; ot < 4; ++ot){
              int orow = oh * 64 + ot * 16 + fr;
              bf16x8 bf_ = *(const bf16x8*)(WT + ((orow * 128 + kb) ^ ((orow & 7) << 4)));
              gd[ot] = mfma16(af, bf_, gd[ot]);
            }
          }
        }
      }
      // gate epilogue: sigmoid -> rhN (o<64), uT (o>=64)
      {
        int oh = w >> 2, ntE = w & 3;
        #pragma unroll
        for (int ot = 0; ot < 4; ++ot){
          int o = oh * 64 + ot * 16 + fr;
          float bias = bg[o];
          float gg[4];
          #pragma unroll
          for (int r = 0; r < 4; ++r) gg[r] = 1.f / (1.f + __expf(-(gd[ot][r] + bias)));
          if (oh == 0){
            #pragma unroll
            for (int r = 0; r < 4; ++r){
              size_t idx = ((size_t)b * NN + n0 + ntE * 16 + ro + r) * NH + o;
              rhN[idx] = (bf16_t)(gg[r] * (float)hNb[idx]);
            }
          } else {
            f32x4 uv = { gg[0], gg[1], gg[2], gg[3] };
            *(f32x4*)&uT[((size_t)b * NH + (o - 64)) * NN + n0 + ntE * 16 + ro] = uv;
          }
        }
      }
      gbarrier(bcnt, bgen);

      // ================= CAND =================
      f32x4 cd[4];
      #pragma unroll
      for (int i = 0; i < 4; ++i) cd[i] = (f32x4){0.f, 0.f, 0.f, 0.f};
      {
        const char* const Sbase = (w >= 4) ? S2R : SR;
        const int arow = (w & 3) * 16 + fr;
        bf16x8 pr[2];
        auto cpref = [&](int ch, int p){
          int m = ch * 64 + lane;
          pr[p] = *(const bf16x8*)&rhN[((size_t)b * NN + m) * NH + w * 8];
        };
        auto cwrite = [&](int p, char* buf){
          #pragma unroll
          for (int q = 0; q < 8; ++q){
            int c = w * 8 + q;
            *(bf16_t*)(buf + ((c * 128 + lane * 2) ^ ((c & 7) << 4))) = pr[p][q];
          }
        };
        auto cmm = [&](const char* buf, int ch){
          #pragma unroll
          for (int ktl = 0; ktl < 2; ++ktl){
            int kb = (ch * 64 + ktl * 32 + ko) * 2;
            bf16x8 af = *(const bf16x8*)(Sbase + ((arow * 1024 + kb) ^ ((arow & 7) << 4)));
            int kl = (ktl * 32 + ko) * 2;
            #pragma unroll
            for (int ct = 0; ct < 4; ++ct){
              int brow = ct * 16 + fr;
              bf16x8 bf_ = *(const bf16x8*)(buf + ((brow * 128 + kl) ^ ((brow & 7) << 4)));
              cd[ct] = mfma16(af, bf_, cd[ct]);
            }
          }
        };
        cpref(0, 0);
        __syncthreads();
        cwrite(0, BQ0);
        cpref(1, 1);
        __syncthreads();
        #pragma unroll
        for (int ch = 0; ch < 8; ++ch){
          cmm((ch & 1) ? BQ1 : BQ0, ch);
          if (ch < 7){
            __syncthreads();
            cwrite((ch + 1) & 1, (ch & 1) ? BQ0 : BQ1);
            if (ch < 6) cpref(ch + 2, ch & 1);
            __syncthreads();
          }
        }
      }
      // cand dense: 6 chunks of 64 f
      f32x4 cdd[2];
      #pragma unroll
      for (int i = 0; i < 2; ++i) cdd[i] = (f32x4){0.f, 0.f, 0.f, 0.f};
      #pragma unroll
      for (int j = 0; j < 6; ++j){
        __syncthreads();
        { // stage Wc chunk [64 o][64 f]
          int o = tid >> 3, gr = tid & 7;
          bf16x8 v = *(const bf16x8*)&Wc[(size_t)o * NF + j * 64 + gr * 8];
          *(bf16x8*)(WT + ((o * 128 + gr * 16) ^ ((o & 7) << 4))) = v;
        }
        if (j == 0){
          int n = tid >> 3, f16 = tid & 7;
          const float* xr = xs + (size_t)(n0 + n) * NH + f16 * 8;
          f32x4 a = *(const f32x4*)xr, b2 = *(const f32x4*)(xr + 4);
          bf16x8 v;
          #pragma unroll
          for (int q = 0; q < 4; ++q){ v[q] = (bf16_t)a[q]; v[q + 4] = (bf16_t)b2[q]; }
          *(bf16x8*)(FT + ((n * 128 + f16 * 16) ^ ((n & 7) << 4))) = v;
        } else if (j == 1){
          int n = tid >> 3, f16 = tid & 7;
          bf16x8 v = *(const bf16x8*)&rhN[((size_t)b * NN + n0 + n) * NH + f16 * 8];
          *(bf16x8*)(FT + ((n * 128 + f16 * 16) ^ ((n & 7) << 4))) = v;
        } else if (j == 2 || j == 3){
          if (w < 4){
            #pragma unroll
            for (int ct = 0; ct < 4; ++ct){
              int c = ct * 16 + fr;
              #pragma unroll
              for (int r = 0; r < 4; ++r){
                int n = (w & 3) * 16 + ro + r;
                float v = (j == 2) ? ga[ct][r] : cd[ct][r];   // t1x | S@rh
                *(bf16_t*)(FT + ((n * 128 + c * 2) ^ ((n & 7) << 4))) = (bf16_t)v;
              }
            }
          }
        } else {
          if (w >= 4){
            #pragma unroll
            for (int ct = 0; ct < 4; ++ct){
              int c = ct * 16 + fr;
              #pragma unroll
              for (int r = 0; r < 4; ++r){
                int n = (w & 3) * 16 + ro + r;
                float base = (j == 4) ? xs[(size_t)(n0 + n) * NH + c]
                                      : (float)rhN[((size_t)b * NN + n0 + n) * NH + c];
                float v = 2.f * ((j == 4) ? ga[ct][r] : cd[ct][r]) - base;
                *(bf16_t*)(FT + ((n * 128 + c * 2) ^ ((n & 7) << 4))) = (bf16_t)v;
              }
            }
          }
        }
        __syncthreads();
        {
          int anr = (w & 3) * 16 + fr, op = w >> 2;
          #pragma unroll
          for (int ktl = 0; ktl < 2; ++ktl){
            int kb = (ktl * 32 + ko) * 2;
            bf16x8 af = *(const bf16x8*)(FT + ((anr * 128 + kb) ^ ((anr & 7) << 4)));
            #pragma unroll
            for (int e = 0; e < 2; ++e){
              int orow = (op * 2 + e) * 16 + fr;
              bf16x8 bf_ = *(const bf16x8*)(WT + ((orow * 128 + kb) ^ ((orow & 7) << 4)));
              cdd[e] = mfma16(af, bf_, cdd[e]);
            }
          }
        }
      }
      __syncthreads();   // protect WT/FT before TT overwrite
      // cand epilogue: tanh + GRU update -> TT
      {
        int ntD = w & 3, op = w >> 2;
        #pragma unroll
        for (int e = 0; e < 2; ++e){
          int o = (op * 2 + e) * 16 + fr;
          float bias = bc[o];
          size_t base = ((size_t)b * NH + o) * NN + n0 + ntD * 16 + ro;
          f32x4 uu = *(const f32x4*)&uT[base];
          f32x4 hh = *(const f32x4*)&hTf[base];
          f32x4 nh;
          #pragma unroll
          for (int r = 0; r < 4; ++r){
            float ez = __expf(2.f * (cdd[e][r] + bias));
            float cc = (ez - 1.f) / (ez + 1.f);
            nh[r] = uu[r] * hh[r] + (1.f - uu[r]) * cc;
          }
          *(f32x4*)&TT[o * 68 + ntD * 16 + ro] = nh;
        }
      }
      __syncthreads();
      { // dump hTf rows
        int o = tid >> 3, cq = tid & 7;
        #pragma unroll
        for (int s = 0; s < 2; ++s){
          int nq = (cq + s * 8) * 4;
          f32x4 v = *(const f32x4*)&TT[o * 68 + nq];
          *(f32x4*)&hTf[((size_t)b * NH + o) * NN + n0 + nq] = v;
        }
      }
      { // dump cur / hNb / finalh (transposed reads from TT)
        int n = lane, ow = w * 8;
        float vv[8];
        #pragma unroll
        for (int q = 0; q < 8; ++q) vv[q] = TT[(ow + q) * 68 + n];
        f32x4 lo = { vv[0], vv[1], vv[2], vv[3] };
        f32x4 hi = { vv[4], vv[5], vv[6], vv[7] };
        float* crow = cur + (size_t)t * NB * NN * NH + ((size_t)b * NN + n0 + n) * NH + ow;
        *(f32x4*)crow = lo; *(f32x4*)(crow + 4) = hi;
        bf16x8 hb;
        #pragma unroll
        for (int q = 0; q < 8; ++q) hb[q] = (bf16_t)vv[q];
        *(bf16x8*)&hNb[((size_t)b * NN + n0 + n) * NH + ow] = hb;
        if (t == 47){
          float* frow = outp + (size_t)l * NB * NN * NH + ((size_t)b * NN + n0 + n) * NH + ow;
          *(f32x4*)frow = lo; *(f32x4*)(frow + 4) = hi;
        }
      }
      gbarrier(bcnt, bgen);
    }
  }
}

// ---------------- host orchestration -----------------------------------------------
extern "C" void kernel_launch(void* const* d_in, const int* in_sizes, int n_in,
                              void* d_out, int out_size, void* d_ws, size_t ws_size,
                              hipStream_t stream){
  const float* inputs = (const float*)d_in[0];
  const float* h0     = (const float*)d_in[1];
  const float* S      = (const float*)d_in[2];
  const float* W_gate = (const float*)d_in[3];
  const float* b_gate = (const float*)d_in[4];
  const float* W_c    = (const float*)d_in[5];
  const float* b_c    = (const float*)d_in[6];
  float* out = (float*)d_out;
  char* ws = (char*)d_ws;

  bf16_t*  Sb  = (bf16_t*)(ws + 0);          // 524288
  bf16_t*  S2b = (bf16_t*)(ws + 524288);     // 524288
  bf16_t*  WgT = (bf16_t*)(ws + 1048576);    // 196608
  bf16_t*  WcT = (bf16_t*)(ws + 1245184);    // 98304
  float*   hTf = (float*) (ws + 1343488);    // 4194304
  bf16_t*  hNb = (bf16_t*)(ws + 5537792);    // 2097152
  bf16_t*  rhN = (bf16_t*)(ws + 7634944);    // 2097152
  float*   uT  = (float*) (ws + 9732096);    // 4194304
  unsigned* bar = (unsigned*)(ws + 13926400);// 4096

  hipMemsetAsync(bar, 0, 4096, stream);
  k_convert_S<<<dim3(256), 256, 0, stream>>>(S, Sb);
  k_s2<<<dim3(1024), 256, 0, stream>>>(S, S2b);
  k_transW<<<dim3((2 * NF * 128 + 255) / 256), 256, 0, stream>>>(W_gate, WgT, 128);
  k_transW<<<dim3((2 * NF * 64 + 255) / 256), 256, 0, stream>>>(W_c, WcT, 64);

  hipFuncSetAttribute((const void*)k_main,
                      hipFuncAttributeMaxDynamicSharedMemorySize, 163840);

  void* args[] = { (void*)&inputs, (void*)&h0, (void*)&Sb, (void*)&S2b,
                   (void*)&WgT, (void*)&WcT, (void*)&b_gate, (void*)&b_c,
                   (void*)&hTf, (void*)&hNb, (void*)&rhN, (void*)&uT,
                   (void*)&bar, (void*)&out };
  hipLaunchCooperativeKernel((void*)k_main, dim3(256), dim3(512), args,
                             163840, stream);
}

// Round 4
// 3214.329 us; speedup vs baseline: 3.6074x; 3.6074x over previous
//
#include <hip/hip_runtime.h>
#include <math.h>

typedef __bf16 bf16_t;
typedef bf16_t bf16x8 __attribute__((ext_vector_type(8)));
typedef float  f32x4  __attribute__((ext_vector_type(4)));
typedef unsigned long long u64_t;

#define NB 32
#define NN 512
#define NH 64
#define TSTEPS 48

static __device__ __forceinline__ f32x4 mfma16(bf16x8 a, bf16x8 b, f32x4 c){
  return __builtin_amdgcn_mfma_f32_16x16x32_bf16(a, b, c, 0, 0, 0);
}
static __device__ __forceinline__ void gload16(char* lds, const char* g){
  __builtin_amdgcn_global_load_lds((const __attribute__((address_space(1))) void*)g,
                                   (__attribute__((address_space(3))) void*)lds, 16, 0, 0);
}
static __device__ __forceinline__ unsigned pack2(float a, float b){
  bf16_t x = (bf16_t)a, y = (bf16_t)b;
  unsigned short ux = __builtin_bit_cast(unsigned short, x);
  unsigned short uy = __builtin_bit_cast(unsigned short, y);
  return (unsigned)ux | ((unsigned)uy << 16);
}

// ---------------- setup kernels ---------------------------------------------------
__global__ __launch_bounds__(256) void k_s2f(const float* __restrict__ S,
                                             float* __restrict__ S2f){
  int idx = blockIdx.x * 256 + threadIdx.x;      // 262144
  int n = idx >> 9, m = idx & 511;
  float acc = 0.f;
  #pragma unroll 8
  for (int k = 0; k < 512; ++k) acc += S[n * 512 + k] * S[k * 512 + m];
  S2f[idx] = acc;
}

// S_cat_pre: 32 rt x 8 kt tiles of 4KB; tile content (rr,kk): byte (rr*128+2kk)^((rr&7)<<4)
__global__ __launch_bounds__(256) void k_prepS(const float* __restrict__ S,
                                               const float* __restrict__ S2f,
                                               char* __restrict__ dst){
  int id = blockIdx.x * 256 + threadIdx.x;       // 524288
  int r = id >> 9, k = id & 511;
  float v = (r < 512) ? S[r * 512 + k] : S2f[(r - 512) * 512 + k];
  int rt = r >> 5, rr = r & 31, kt = k >> 6, kk = k & 63;
  size_t off = ((size_t)(rt * 8 + kt)) * 4096 + (size_t)(((rr * 128 + 2 * kk)) ^ ((rr & 7) << 4));
  *(bf16_t*)(dst + off) = (bf16_t)v;
}

// folded + transposed + pre-swizzled weights; tiles [OD][64k], 6 per layer
__global__ __launch_bounds__(256) void k_prepW(const float* __restrict__ W,
                                               char* __restrict__ dst, int OD){
  int id = blockIdx.x * 256 + threadIdx.x;
  int total = 2 * 384 * OD;
  if (id >= total) return;
  int o = id % OD, rest = id / OD, f = rest % 384, l = rest / 384;
  const float* Wl = W + (size_t)l * 384 * OD;
  float v;
  if (f < 128)      v = Wl[f * OD + o] - Wl[(256 + f) * OD + o];
  else if (f < 256) v = Wl[f * OD + o];
  else              v = 2.f * Wl[f * OD + o];
  int kt = f >> 6, kk = f & 63;
  size_t off = (size_t)l * (6 * OD * 128) + (size_t)kt * (OD * 128)
             + (size_t)(((o * 128 + 2 * kk)) ^ ((o & 7) << 4));
  *(bf16_t*)(dst + off) = (bf16_t)v;
}

__global__ __launch_bounds__(256) void k_hinit(const float* __restrict__ h0l,
                                               float* __restrict__ hNf,
                                               bf16_t* __restrict__ hN){
  int i = (blockIdx.x * 256 + threadIdx.x) * 8;   // 1048576 elems
  f32x4 a = *(const f32x4*)&h0l[i], b = *(const f32x4*)&h0l[i + 4];
  *(f32x4*)&hNf[i] = a; *(f32x4*)&hNf[i + 4] = b;
  bf16x8 v;
  #pragma unroll
  for (int q = 0; q < 4; ++q){ v[q] = (bf16_t)a[q]; v[q + 4] = (bf16_t)b[q]; }
  *(bf16x8*)&hN[i] = v;
}

// ---------------- gate kernel -----------------------------------------------------
// block: 32 output nodes (n0) x 1 batch. diffusion [S;S2]@[x h] -> feat -> dense ->
// sigmoid -> rhN / uN; dumps Dx (Sx,S2x) for cand.
__global__ __launch_bounds__(512, 4) void k_gate(
    const float* __restrict__ xall, int t,
    const bf16_t* __restrict__ hN, const char* __restrict__ SP,
    const char* __restrict__ WgP, const float* __restrict__ bg,
    bf16_t* __restrict__ rhN, float* __restrict__ uN, bf16_t* __restrict__ Dx)
{
  __shared__ char smem[57344];
  char* const A0 = smem;            char* const A1 = smem + 8192;
  char* const B0 = smem + 16384;    char* const B1 = smem + 32768;
  char* const FT = smem;                                  // feat 32x384 swz (24576)
  char* const W0 = smem + 24576;    char* const W1 = smem + 40960;
  char* const RL = smem + 24576;                          // rh tile 4KB
  char* const UL = smem + 28672;                          // u tile 8KB

  const int L = blockIdx.x;
  const int b  = (L & 7) + (((L >> 3) >> 4) << 3);        // bijective XCD grouping
  const int bx = (L >> 3) & 15;
  const int n0 = bx * 32;
  const int tid = threadIdx.x, lane = tid & 63, w = tid >> 6;
  const int fr = lane & 15, ko = (lane >> 4) * 8, ro = (lane >> 4) * 4;
  const int pp = tid >> 4, q4 = tid & 15;

  const float*  xs = xall + ((size_t)t * NB + b) * NN * NH;
  const bf16_t* hb = hN + (size_t)b * NN * NH;

  const int wr = w >> 2, wc = w & 3;
  f32x4 acc[2][2] = {};
  f32x4 rx0, rx1; u64_t rh0, rh1;

  auto ldB = [&](int kt){
    int m = kt * 64 + 2 * pp;
    const float* xr = xs + (size_t)m * NH + q4 * 4;
    rx0 = *(const f32x4*)xr; rx1 = *(const f32x4*)(xr + NH);
    const bf16_t* hr = hb + (size_t)m * NH + q4 * 4;
    rh0 = *(const u64_t*)hr; rh1 = *(const u64_t*)(hr + NH);
  };
  auto stB = [&](char* Bb){
    int mby = 4 * pp;
    #pragma unroll
    for (int i = 0; i < 4; ++i){
      int c = q4 * 4 + i;
      *(unsigned*)(Bb + ((c * 128 + mby) ^ (((c >> 2) & 7) << 4))) = pack2(rx0[i], rx1[i]);
      int c2 = c + 64;
      unsigned uh = (unsigned)((rh0 >> (16 * i)) & 0xffffULL)
                  | ((unsigned)((rh1 >> (16 * i)) & 0xffffULL) << 16);
      *(unsigned*)(Bb + ((c2 * 128 + mby) ^ (((c2 >> 2) & 7) << 4))) = uh;
    }
  };
  auto gloadA = [&](int kt, char* Ab){
    if (w < 4){
      gload16(Ab + w * 1024, SP + ((size_t)(bx * 8 + kt)) * 4096 + (w * 64 + lane) * 16);
    } else {
      gload16(Ab + 4096 + (w - 4) * 1024,
              SP + ((size_t)((16 + bx) * 8 + kt)) * 4096 + ((w - 4) * 64 + lane) * 16);
    }
  };
  auto dmm = [&](const char* Ab, const char* Bb){
    #pragma unroll
    for (int kh = 0; kh < 2; ++kh){
      int kb = 2 * (kh * 32 + ko);
      bf16x8 af[2], bf_[2];
      #pragma unroll
      for (int fm = 0; fm < 2; ++fm){
        int r = wr * 32 + fm * 16 + fr;
        af[fm] = *(const bf16x8*)(Ab + ((r * 128 + kb) ^ ((r & 7) << 4)));
      }
      #pragma unroll
      for (int fc = 0; fc < 2; ++fc){
        int c = wc * 32 + fc * 16 + fr;
        bf_[fc] = *(const bf16x8*)(Bb + ((c * 128 + kb) ^ (((c >> 2) & 7) << 4)));
      }
      #pragma unroll
      for (int fm = 0; fm < 2; ++fm)
        #pragma unroll
        for (int fc = 0; fc < 2; ++fc)
          acc[fm][fc] = mfma16(af[fm], bf_[fc], acc[fm][fc]);
    }
  };

  ldB(0); stB(B0); gloadA(0, A0);
  __syncthreads();
  ldB(1); stB(B1); gloadA(1, A1);
  __syncthreads();
  ldB(2);
  #pragma unroll
  for (int kt = 0; kt < 8; ++kt){
    dmm((kt & 1) ? A1 : A0, (kt & 1) ? B1 : B0);
    __syncthreads();
    if (kt < 6){
      stB((kt & 1) ? B1 : B0);
      gloadA(kt + 2, (kt & 1) ? A1 : A0);
      if (kt < 5) ldB(kt + 3);
    }
    __syncthreads();
  }

  auto gloadW = [&](int j, char* Wb){
    const char* src = WgP + (size_t)j * 16384 + (w * 64 + lane) * 16;
    gload16(Wb + w * 1024, src);
    gload16(Wb + 8192 + w * 1024, src + 8192);
  };

  // ---- feat fill ----
  {
    int row = tid >> 4, c8 = (tid & 15) * 8;
    char* fdst = FT + (((row * 768 + 2 * c8)) ^ ((row & 7) << 4));
    if (c8 < 64){
      const float* xr = xs + (size_t)(n0 + row) * NH + c8;
      f32x4 a = *(const f32x4*)xr, bq = *(const f32x4*)(xr + 4);
      bf16x8 v;
      #pragma unroll
      for (int q = 0; q < 4; ++q){ v[q] = (bf16_t)a[q]; v[q + 4] = (bf16_t)bq[q]; }
      *(bf16x8*)fdst = v;
    } else {
      *(bf16x8*)fdst = *(const bf16x8*)(hb + (size_t)(n0 + row) * NH + (c8 - 64));
    }
  }
  #pragma unroll
  for (int fm = 0; fm < 2; ++fm)
    #pragma unroll
    for (int fc = 0; fc < 2; ++fc)
      #pragma unroll
      for (int q = 0; q < 4; ++q){
        int dr = wr * 32 + fm * 16 + ro + q;
        int nn = dr & 31;
        int col = ((dr < 32) ? 128 : 256) + wc * 32 + fc * 16 + fr;
        *(bf16_t*)(FT + (((nn * 768 + 2 * col)) ^ ((nn & 7) << 4))) = (bf16_t)acc[fm][fc][q];
      }
  gloadW(0, W0);
  __syncthreads();

  // Dx dump
  {
    int row = tid >> 4, d8 = (tid & 15) * 8;
    int col = (d8 < 64) ? 128 + d8 : 256 + (d8 - 64);
    bf16x8 v = *(const bf16x8*)(FT + (((row * 768 + 2 * col)) ^ ((row & 7) << 4)));
    *(bf16x8*)&Dx[((size_t)b * NN + n0 + row) * 128 + d8] = v;
  }

  // ---- dense ----
  const int wn = w & 1, wo = w >> 1;
  f32x4 gd[2] = {};
  #pragma unroll
  for (int j = 0; j < 6; ++j){
    if (j < 5) gloadW(j + 1, ((j + 1) & 1) ? W1 : W0);
    const char* Wb = (j & 1) ? W1 : W0;
    #pragma unroll
    for (int kh = 0; kh < 2; ++kh){
      int kb = 2 * (j * 64 + kh * 32 + ko);
      int r = wn * 16 + fr;
      bf16x8 af = *(const bf16x8*)(FT + ((r * 768 + kb) ^ ((r & 7) << 4)));
      int kbw = 2 * (kh * 32 + ko);
      #pragma unroll
      for (int fo = 0; fo < 2; ++fo){
        int orow = wo * 32 + fo * 16 + fr;
        bf16x8 bw = *(const bf16x8*)(Wb + ((orow * 128 + kbw) ^ ((orow & 7) << 4)));
        gd[fo] = mfma16(af, bw, gd[fo]);
      }
    }
    __syncthreads();
  }

  // ---- epilogue ----
  #pragma unroll
  for (int fo = 0; fo < 2; ++fo){
    int o = wo * 32 + fo * 16 + fr;
    float bias = bg[o];
    #pragma unroll
    for (int q = 0; q < 4; ++q){
      int nn = wn * 16 + ro + q;
      float g = 1.f / (1.f + __expf(-(gd[fo][q] + bias)));
      if (o < 64){
        float hv = (float)*(const bf16_t*)(FT + (((nn * 768 + 2 * (64 + o))) ^ ((nn & 7) << 4)));
        *(bf16_t*)(RL + ((nn * 128 + 2 * o) ^ ((nn & 7) << 4))) = (bf16_t)(g * hv);
      } else {
        *(float*)(UL + ((nn * 256 + 4 * (o - 64)) ^ ((nn & 7) << 5))) = g;
      }
    }
  }
  __syncthreads();
  if (tid < 256){
    int row = tid >> 3, o8 = (tid & 7) * 8;
    bf16x8 v = *(const bf16x8*)(RL + ((row * 128 + 2 * o8) ^ ((row & 7) << 4)));
    *(bf16x8*)&rhN[((size_t)b * NN + n0 + row) * NH + o8] = v;
  } else {
    int t2 = tid - 256;
    int row = t2 >> 3, o8 = (t2 & 7) * 8;
    int base = (row * 256 + 4 * o8) ^ ((row & 7) << 5);
    f32x4 u0 = *(const f32x4*)(UL + base);
    f32x4 u1 = *(const f32x4*)(UL + base + 16);
    size_t gi = ((size_t)b * NN + n0 + row) * NH + o8;
    *(f32x4*)&uN[gi] = u0; *(f32x4*)&uN[gi + 4] = u1;
  }
}

// ---------------- candidate kernel ------------------------------------------------
__global__ __launch_bounds__(512, 4) void k_cand(
    const float* __restrict__ xall, int t,
    const bf16_t* __restrict__ rhN, const bf16_t* __restrict__ Dx,
    const char* __restrict__ SP, const char* __restrict__ WcP,
    const float* __restrict__ bc, const float* __restrict__ uN,
    float* __restrict__ hNf, bf16_t* __restrict__ hN,
    float* __restrict__ curp, float* __restrict__ fin)
{
  __shared__ char smem[40960];
  char* const A0 = smem;            char* const A1 = smem + 8192;
  char* const B0 = smem + 16384;    char* const B1 = smem + 24576;
  char* const FT = smem;                                  // feat 32x384 swz
  char* const W0 = smem + 24576;    char* const W1 = smem + 32768;
  char* const CL = smem + 24576;                          // c tile f32 8KB

  const int L = blockIdx.x;
  const int b  = (L & 7) + (((L >> 3) >> 4) << 3);
  const int bx = (L >> 3) & 15;
  const int n0 = bx * 32;
  const int tid = threadIdx.x, lane = tid & 63, w = tid >> 6;
  const int fr = lane & 15, ko = (lane >> 4) * 8, ro = (lane >> 4) * 4;
  const int pp = tid >> 4, q4 = tid & 15;

  const float*  xs = xall + ((size_t)t * NB + b) * NN * NH;
  const bf16_t* rb = rhN + (size_t)b * NN * NH;

  const int wr = w >> 2, wc = w & 3;
  f32x4 ca[2] = {};
  u64_t rh0, rh1;

  auto ldB = [&](int kt){
    int m = kt * 64 + 2 * pp;
    const bf16_t* rr = rb + (size_t)m * NH + q4 * 4;
    rh0 = *(const u64_t*)rr; rh1 = *(const u64_t*)(rr + NH);
  };
  auto stB = [&](char* Bb){
    int mby = 4 * pp;
    #pragma unroll
    for (int i = 0; i < 4; ++i){
      int c = q4 * 4 + i;
      unsigned u = (unsigned)((rh0 >> (16 * i)) & 0xffffULL)
                 | ((unsigned)((rh1 >> (16 * i)) & 0xffffULL) << 16);
      *(unsigned*)(Bb + ((c * 128 + mby) ^ (((c >> 2) & 7) << 4))) = u;
    }
  };
  auto gloadA = [&](int kt, char* Ab){
    if (w < 4){
      gload16(Ab + w * 1024, SP + ((size_t)(bx * 8 + kt)) * 4096 + (w * 64 + lane) * 16);
    } else {
      gload16(Ab + 4096 + (w - 4) * 1024,
              SP + ((size_t)((16 + bx) * 8 + kt)) * 4096 + ((w - 4) * 64 + lane) * 16);
    }
  };
  auto cmm = [&](const char* Ab, const char* Bb){
    #pragma unroll
    for (int kh = 0; kh < 2; ++kh){
      int kb = 2 * (kh * 32 + ko);
      int c = wc * 16 + fr;
      bf16x8 bf_ = *(const bf16x8*)(Bb + ((c * 128 + kb) ^ (((c >> 2) & 7) << 4)));
      #pragma unroll
      for (int fm = 0; fm < 2; ++fm){
        int r = wr * 32 + fm * 16 + fr;
        bf16x8 af = *(const bf16x8*)(Ab + ((r * 128 + kb) ^ ((r & 7) << 4)));
        ca[fm] = mfma16(af, bf_, ca[fm]);
      }
    }
  };

  ldB(0); stB(B0); gloadA(0, A0);
  __syncthreads();
  ldB(1); stB(B1); gloadA(1, A1);
  __syncthreads();
  ldB(2);
  #pragma unroll
  for (int kt = 0; kt < 8; ++kt){
    cmm((kt & 1) ? A1 : A0, (kt & 1) ? B1 : B0);
    __syncthreads();
    if (kt < 6){
      stB((kt & 1) ? B1 : B0);
      gloadA(kt + 2, (kt & 1) ? A1 : A0);
      if (kt < 5) ldB(kt + 3);
    }
    __syncthreads();
  }

  auto gloadW = [&](int j, char* Wb){
    gload16(Wb + w * 1024, WcP + (size_t)j * 8192 + (w * 64 + lane) * 16);
  };

  // ---- feat fill ----
  {
    int row = tid >> 4, c8 = (tid & 15) * 8;
    char* fdst = FT + (((row * 768 + 2 * c8)) ^ ((row & 7) << 4));
    if (c8 < 64){
      const float* xr = xs + (size_t)(n0 + row) * NH + c8;
      f32x4 a = *(const f32x4*)xr, bq = *(const f32x4*)(xr + 4);
      bf16x8 v;
      #pragma unroll
      for (int q = 0; q < 4; ++q){ v[q] = (bf16_t)a[q]; v[q + 4] = (bf16_t)bq[q]; }
      *(bf16x8*)fdst = v;
    } else {
      *(bf16x8*)fdst = *(const bf16x8*)(rb + (size_t)(n0 + row) * NH + (c8 - 64));
    }
    int col = (c8 < 64) ? 128 + c8 : 256 + (c8 - 64);
    bf16x8 dv = *(const bf16x8*)&Dx[((size_t)b * NN + n0 + row) * 128 + c8];
    *(bf16x8*)(FT + (((row * 768 + 2 * col)) ^ ((row & 7) << 4))) = dv;
  }
  #pragma unroll
  for (int fm = 0; fm < 2; ++fm)
    #pragma unroll
    for (int q = 0; q < 4; ++q){
      int dr = wr * 32 + fm * 16 + ro + q;
      int nn = dr & 31;
      int col = ((dr < 32) ? 192 : 320) + wc * 16 + fr;
      *(bf16_t*)(FT + (((nn * 768 + 2 * col)) ^ ((nn & 7) << 4))) = (bf16_t)ca[fm][q];
    }
  gloadW(0, W0);
  __syncthreads();

  // ---- dense ----
  const int wn = w & 1, wo = w >> 1;
  f32x4 cd = {};
  #pragma unroll
  for (int j = 0; j < 6; ++j){
    if (j < 5) gloadW(j + 1, ((j + 1) & 1) ? W1 : W0);
    const char* Wb = (j & 1) ? W1 : W0;
    #pragma unroll
    for (int kh = 0; kh < 2; ++kh){
      int kb = 2 * (j * 64 + kh * 32 + ko);
      int r = wn * 16 + fr;
      bf16x8 af = *(const bf16x8*)(FT + ((r * 768 + kb) ^ ((r & 7) << 4)));
      int kbw = 2 * (kh * 32 + ko);
      int orow = wo * 16 + fr;
      bf16x8 bw = *(const bf16x8*)(Wb + ((orow * 128 + kbw) ^ ((orow & 7) << 4)));
      cd = mfma16(af, bw, cd);
    }
    __syncthreads();
  }

  // ---- epilogue: tanh -> CL ----
  {
    int o = wo * 16 + fr;
    float bias = bc[o];
    #pragma unroll
    for (int q = 0; q < 4; ++q){
      int nn = wn * 16 + ro + q;
      float e = __expf(2.f * (cd[q] + bias));
      *(float*)(CL + ((nn * 256 + 4 * o) ^ ((nn & 7) << 5))) = (e - 1.f) / (e + 1.f);
    }
  }
  __syncthreads();
  if (tid < 256){
    int row = tid >> 3, o8 = (tid & 7) * 8;
    int base = (row * 256 + 4 * o8) ^ ((row & 7) << 5);
    f32x4 c0 = *(const f32x4*)(CL + base);
    f32x4 c1 = *(const f32x4*)(CL + base + 16);
    size_t gi = ((size_t)b * NN + n0 + row) * NH + o8;
    f32x4 u0 = *(const f32x4*)&uN[gi], u1 = *(const f32x4*)&uN[gi + 4];
    f32x4 h0v = *(const f32x4*)&hNf[gi], h1v = *(const f32x4*)&hNf[gi + 4];
    f32x4 n0v, n1v;
    #pragma unroll
    for (int q = 0; q < 4; ++q){
      n0v[q] = u0[q] * h0v[q] + (1.f - u0[q]) * c0[q];
      n1v[q] = u1[q] * h1v[q] + (1.f - u1[q]) * c1[q];
    }
    *(f32x4*)&hNf[gi] = n0v; *(f32x4*)&hNf[gi + 4] = n1v;
    bf16x8 hb;
    #pragma unroll
    for (int q = 0; q < 4; ++q){ hb[q] = (bf16_t)n0v[q]; hb[q + 4] = (bf16_t)n1v[q]; }
    *(bf16x8*)&hN[gi] = hb;
    float* cr = curp + (size_t)t * NB * NN * NH + gi;
    *(f32x4*)cr = n0v; *(f32x4*)(cr + 4) = n1v;
    if (t == TSTEPS - 1){
      *(f32x4*)&fin[gi] = n0v; *(f32x4*)&fin[gi + 4] = n1v;
    }
  }
}

// ---------------- host orchestration ----------------------------------------------
extern "C" void kernel_launch(void* const* d_in, const int* in_sizes, int n_in,
                              void* d_out, int out_size, void* d_ws, size_t ws_size,
                              hipStream_t stream){
  const float* inputs = (const float*)d_in[0];
  const float* h0     = (const float*)d_in[1];
  const float* S      = (const float*)d_in[2];
  const float* W_gate = (const float*)d_in[3];
  const float* b_gate = (const float*)d_in[4];
  const float* W_c    = (const float*)d_in[5];
  const float* b_c    = (const float*)d_in[6];
  float* out = (float*)d_out;
  char* ws = (char*)d_ws;

  float*  S2f = (float*) (ws + 0);          // 1048576
  char*   SP  =          ws + 1048576;      // 1048576
  char*   WgP =          ws + 2097152;      // 196608
  char*   WcP =          ws + 2293760;      // 98304
  float*  hNf = (float*) (ws + 2392064);    // 4194304
  bf16_t* hN  = (bf16_t*)(ws + 6586368);    // 2097152
  bf16_t* rhN = (bf16_t*)(ws + 8683520);    // 2097152
  float*  uN  = (float*) (ws + 10780672);   // 4194304
  bf16_t* Dx  = (bf16_t*)(ws + 14974976);   // 4194304 -> end 19169280

  float* finalh = out;                                 // [2][B][N*H]
  float* cur    = out + (size_t)2 * NB * NN * NH;      // [T][B][N*H]

  k_s2f<<<dim3(1024), 256, 0, stream>>>(S, S2f);
  k_prepS<<<dim3(2048), 256, 0, stream>>>(S, S2f, SP);
  k_prepW<<<dim3(384), 256, 0, stream>>>(W_gate, WgP, 128);
  k_prepW<<<dim3(192), 256, 0, stream>>>(W_c, WcP, 64);

  for (int l = 0; l < 2; ++l){
    k_hinit<<<dim3(512), 256, 0, stream>>>(h0 + (size_t)l * NB * NN * NH, hNf, hN);
    const float* xa = (l == 0) ? inputs : cur;
    const char* Wg_l = WgP + (size_t)l * 98304;
    const char* Wc_l = WcP + (size_t)l * 49152;
    const float* bg_l = b_gate + l * 128;
    const float* bc_l = b_c + l * 64;
    float* fin_l = finalh + (size_t)l * NB * NN * NH;
    for (int t = 0; t < TSTEPS; ++t){
      k_gate<<<dim3(512), 512, 0, stream>>>(xa, t, hN, SP, Wg_l, bg_l, rhN, uN, Dx);
      k_cand<<<dim3(512), 512, 0, stream>>>(xa, t, rhN, Dx, SP, Wc_l, bc_l, uN,
                                            hNf, hN, cur, fin_l);
    }
  }
}